// Round 1
// baseline (15.017 us; speedup 1.0000x reference)
//
#include <hip/hip_runtime.h>

// CenterLoss: loss = sum_i clip(||x_i||^2 + ||c_{y_i}||^2 - 2 x_i·c_{y_i}, 1e-12, 1e12) / BS
//                    + (C_OUT-1)*1e-12
// x: (32768,128) f32, labels: (32768,) int, centers: (100000,128) f32 -> scalar f32.

#define BS_N     32768
#define DIM      128
#define C_OUT    100000
#define CLAMP_MIN 1e-12f
#define CLAMP_MAX 1e12f

constexpr int BLOCKS  = 512;
constexpr int THREADS = 256;   // 4 waves/block

__global__ __launch_bounds__(THREADS)
void center_loss_partial(const float* __restrict__ x,
                         const int* __restrict__ labels,
                         const float* __restrict__ centers,
                         float* __restrict__ partials) {
    const int tid     = threadIdx.x;
    const int wave    = tid >> 6;        // 0..3
    const int lane    = tid & 63;
    const int half    = lane >> 5;       // 0 or 1: which row of the pair
    const int sublane = lane & 31;       // position within the 32-lane row group

    const int waves_per_block = THREADS >> 6;                 // 4
    const int row_stride      = gridDim.x * waves_per_block * 2;  // rows per grid sweep

    float acc = 0.0f;

    for (int row = (blockIdx.x * waves_per_block + wave) * 2 + half;
         row < BS_N; row += row_stride) {
        const int lbl = labels[row];
        const float4* __restrict__ xr =
            reinterpret_cast<const float4*>(x + (size_t)row * DIM);
        const float4* __restrict__ cr =
            reinterpret_cast<const float4*>(centers + (size_t)lbl * DIM);

        const float4 xv = xr[sublane];
        const float4 cv = cr[sublane];

        // ||x||^2 + ||c||^2 - 2 x·c, elementwise partial over this lane's 4 elems
        float s;
        s  = xv.x * xv.x + cv.x * cv.x - 2.0f * xv.x * cv.x;
        s += xv.y * xv.y + cv.y * cv.y - 2.0f * xv.y * cv.y;
        s += xv.z * xv.z + cv.z * cv.z - 2.0f * xv.z * cv.z;
        s += xv.w * xv.w + cv.w * cv.w - 2.0f * xv.w * cv.w;

        // reduce across the 32 lanes owning this row (xor masks <32 stay in-group)
        #pragma unroll
        for (int off = 1; off < 32; off <<= 1)
            s += __shfl_xor(s, off, 64);

        if (sublane == 0) {
            s = fminf(fmaxf(s, CLAMP_MIN), CLAMP_MAX);
            acc += s;
        }
    }

    // block reduction (deterministic tree)
    __shared__ float red[THREADS];
    red[tid] = acc;
    __syncthreads();
    #pragma unroll
    for (int stride = THREADS / 2; stride > 0; stride >>= 1) {
        if (tid < stride) red[tid] += red[tid + stride];
        __syncthreads();
    }
    if (tid == 0) partials[blockIdx.x] = red[0];
}

__global__ __launch_bounds__(256)
void center_loss_final(const float* __restrict__ partials,
                       float* __restrict__ out) {
    const int tid = threadIdx.x;
    float a = 0.0f;
    for (int i = tid; i < BLOCKS; i += 256) a += partials[i];

    __shared__ float red[256];
    red[tid] = a;
    __syncthreads();
    #pragma unroll
    for (int stride = 128; stride > 0; stride >>= 1) {
        if (tid < stride) red[tid] += red[tid + stride];
        __syncthreads();
    }
    if (tid == 0) {
        const float k = (float)((double)(C_OUT - 1) * 1e-12);  // 9.9999e-8
        out[0] = red[0] / (float)BS_N + k;
    }
}

extern "C" void kernel_launch(void* const* d_in, const int* in_sizes, int n_in,
                              void* d_out, int out_size, void* d_ws, size_t ws_size,
                              hipStream_t stream) {
    const float* x       = (const float*)d_in[0];
    const int*   labels  = (const int*)d_in[1];
    const float* centers = (const float*)d_in[2];
    float*       out     = (float*)d_out;
    float*       partials = (float*)d_ws;   // BLOCKS floats = 2 KB scratch

    center_loss_partial<<<BLOCKS, THREADS, 0, stream>>>(x, labels, centers, partials);
    center_loss_final<<<1, 256, 0, stream>>>(partials, out);
}